// Round 1
// 443.595 us; speedup vs baseline: 1.0983x; 1.0983x over previous
//
#include <hip/hip_runtime.h>
#include <hip/hip_bf16.h>
#include <stdint.h>

typedef __attribute__((ext_vector_type(8))) short short8;
typedef __attribute__((ext_vector_type(4))) float floatx4;

// ---- problem constants ----
constexpr int TD    = 1024;   // token dim
constexpr int E3    = 1536;   // 3*inner
constexpr int INNER = 512;
constexpr int NW    = 512;    // windows
constexpr int M_    = NW * 64; // 32768 tokens

// K-order permutation: reference d = p1*256 + p2*64 + c  <->  d' = c*16 + p1*4 + p2

// ---- workspace layout (bytes) ----
constexpr size_t OFF_TOKA = 0;                                 // tokens bf16 [M, 1024]; oattn aliases later
constexpr size_t OFF_QKV  = (size_t)M_ * TD * 2;               // qkv bf16 [M, 1536]
constexpr size_t OFF_WQT  = OFF_QKV + (size_t)M_ * E3 * 2;     // w_qkv^T bf16 [1536, 1024]
constexpr size_t OFF_WOT  = OFF_WQT + (size_t)E3 * TD * 2;     // w_out^T bf16 [1024, 512]
constexpr size_t OFF_BO   = OFF_WOT + (size_t)TD * INNER * 2;  // bias' fp32 [1024]
constexpr size_t WS_NEED  = OFF_BO + TD * 4;

__device__ __forceinline__ void gl_lds16(const void* g, void* l) {
  __builtin_amdgcn_global_load_lds(
      (const __attribute__((address_space(1))) void*)g,
      (__attribute__((address_space(3))) void*)l, 16, 0, 0);
}

// ---- patchify: x [8,64,256,256] -> tokens bf16 [M, 1024] in d' order ----
__global__ __launch_bounds__(256) void k_patchify(const float* __restrict__ x,
                                                  __hip_bfloat16* __restrict__ tokA) {
  __shared__ __hip_bfloat16 tok[8][1032];
  const int bid = blockIdx.x;
  const int n = bid >> 3, i = bid & 7;
  const int b = n >> 6, h1 = (n >> 3) & 7, w1 = n & 7;
  const int tid = threadIdx.x;
  for (int it = 0; it < 8; ++it) {
    int idx = it * 256 + tid;
    int w4 = idx & 7, p1 = (idx >> 3) & 3, c = idx >> 5;
    int h = h1 * 32 + i * 4 + p1;
    const float4 v = *(const float4*)&x[(((b * 64 + c) * 256 + h) * 256 + w1 * 32 + w4 * 4)];
    __hip_bfloat16* dst = &tok[w4][c * 16 + p1 * 4];
    dst[0] = __float2bfloat16(v.x);
    dst[1] = __float2bfloat16(v.y);
    dst[2] = __float2bfloat16(v.z);
    dst[3] = __float2bfloat16(v.w);
  }
  __syncthreads();
  for (int it = 0; it < 4; ++it) {
    int idx = it * 256 + tid;
    int ch = idx & 127, j = idx >> 7;
    uint4 v = *(const uint4*)&tok[j][ch * 8];
    *(uint4*)&tokA[(size_t)(n * 64 + i * 8 + j) * 1024 + ch * 8] = v;
  }
}

// ---- w_qkv [1024 d][1536 e] fp32 -> wqT bf16 [1536 e][1024 d'] ----
__global__ __launch_bounds__(256) void k_perm_wqkv(const float* __restrict__ wqkv,
                                                   __hip_bfloat16* __restrict__ wqT) {
  __shared__ __hip_bfloat16 wt[16][1032];
  const int e0 = blockIdx.x * 16, tid = threadIdx.x;
  for (int it = 0; it < 64; ++it) {
    int idx = it * 256 + tid;
    int e = idx & 15, d = idx >> 4;
    float v = wqkv[d * 1536 + e0 + e];
    int p1 = d >> 8, p2 = (d >> 6) & 3, c = d & 63;
    wt[e][c * 16 + p1 * 4 + p2] = __float2bfloat16(v);
  }
  __syncthreads();
  for (int it = 0; it < 8; ++it) {
    int idx = it * 256 + tid;
    int ch = idx & 127, e = idx >> 7;
    uint4 v = *(const uint4*)&wt[e][ch * 8];
    *(uint4*)&wqT[(size_t)(e0 + e) * 1024 + ch * 8] = v;
  }
}

// ---- w_out [512 e][1024 d] fp32 -> woT bf16 [1024 d'][512 e] ----
__global__ __launch_bounds__(256) void k_perm_wout(const float* __restrict__ wout,
                                                   __hip_bfloat16* __restrict__ woT) {
  __shared__ __hip_bfloat16 wt[16][1032];
  const int e0 = blockIdx.x * 16, tid = threadIdx.x;
  for (int it = 0; it < 64; ++it) {
    int idx = it * 256 + tid;
    int d = idx & 1023, e = idx >> 10;
    float v = wout[(e0 + e) * 1024 + d];
    int p1 = d >> 8, p2 = (d >> 6) & 3, c = d & 63;
    wt[e][c * 16 + p1 * 4 + p2] = __float2bfloat16(v);
  }
  __syncthreads();
  for (int it = 0; it < 64; ++it) {
    int idx = it * 256 + tid;
    int e = idx & 15, dp = idx >> 4;
    woT[(size_t)dp * 512 + e0 + e] = wt[e][dp];
  }
}

__global__ __launch_bounds__(256) void k_perm_bias(const float* __restrict__ bout,
                                                   float* __restrict__ boP) {
  int dp = blockIdx.x * 256 + threadIdx.x;
  int c = dp >> 4, p1 = (dp >> 2) & 3, p2 = dp & 3;
  boP[dp] = bout[p1 * 256 + p2 * 64 + c];
}

// ============================================================================
// 256x256 8-phase GEMM core (T2+T3+T4+T5).
//   BM=BN=256, BK=64, 512 threads = 8 waves (2M x 4N). LDS = 128 KiB
//   (2 dbuf x [256][64] x {A,B}). Per wave: 128x64 output = acc[8][4].
//   Phase q of a 4-phase group computes m-frags {2q,2q+1} x all 4 n-frags
//   x full K=64 (16 MFMA). All B-frags -> regs at q==0 (so B regions die
//   after phase 1 of their group); A staged as quad-pair chunks
//   (chunk0 = rows 0-63 & 128-191, dead after phase 2; chunk1 after phase 4).
//   Stage schedule (1 half-tile = 2 gl_lds/thread per phase):
//     ph1: A2(t+1)->buf1 | ph2: B0(t+2)->buf0 | ph3: B1(t+2) | ph4: A1(t+2), vmcnt(6)
//     ph5: A2(t+2)       | ph6: B0(t+3)->buf1 | ph7: B1(t+3) | ph8: A1(t+3), vmcnt(6)
//   vmcnt(6) leaves the 3 newest stages in flight; everything a group reads
//   landed >= one full group earlier. Never vmcnt(0) except last iteration.
// ============================================================================
template<int K>
__device__ __forceinline__ void gemm256_acc(
    const __hip_bfloat16* __restrict__ A,
    const __hip_bfloat16* __restrict__ Bt,
    int m0, int n0, int tid,
    __hip_bfloat16 (*As)[256][64], __hip_bfloat16 (*Bs)[256][64],
    floatx4 (&acc)[8][4])
{
  const int lane = tid & 63, wid = tid >> 6;
  const int wm = wid >> 2, wn = wid & 3;
  const int l15 = lane & 15, quad = lane >> 4;

  // stage one B half-tile (rows half*128..+128) of K-tile `tile` into Bs[buf]
  auto stageB = [&](int tile, int half, int buf) {
#pragma unroll
    for (int j = 0; j < 2; ++j) {
      int idx = j * 512 + tid;            // 0..1023
      int rl = idx >> 3, slot = idx & 7;
      int r = half * 128 + rl;
      int ch = slot ^ (r & 7);            // pre-swizzled global chunk
      gl_lds16(&Bt[(size_t)(n0 + r) * K + tile * 64 + ch * 8],
               (char*)&Bs[buf][0][0] + half * 16384 + idx * 16);
    }
  };
  // stage one A quad-chunk (rows chunk*64..+64 and 128+chunk*64..+64)
  auto stageA = [&](int tile, int chunk, int buf) {
#pragma unroll
    for (int j = 0; j < 2; ++j) {
      int rl = tid >> 3, slot = tid & 7;  // 64 rows per round
      int r = j * 128 + chunk * 64 + rl;
      int ch = slot ^ (r & 7);
      gl_lds16(&A[(size_t)(m0 + r) * K + tile * 64 + ch * 8],
               (char*)&As[buf][0][0] + j * 16384 + chunk * 8192 + tid * 16);
    }
  };

  short8 bf[4][2];   // B frags for current group (all n, both k-halves)

#define PH(BUF, Q, STAGE, VMW)                                                    \
  do {                                                                            \
    short8 af[2][2];                                                              \
    _Pragma("unroll") for (int m2 = 0; m2 < 2; ++m2) {                            \
      const int r = wm * 128 + (2 * (Q) + m2) * 16 + l15;                         \
      _Pragma("unroll") for (int kh = 0; kh < 2; ++kh)                            \
        af[m2][kh] = *(const short8*)&As[BUF][r][((kh * 4 + quad) ^ (r & 7)) * 8];\
    }                                                                             \
    if ((Q) == 0) {                                                               \
      _Pragma("unroll") for (int n = 0; n < 4; ++n) {                             \
        const int rb = wn * 64 + n * 16 + l15;                                    \
        _Pragma("unroll") for (int kh = 0; kh < 2; ++kh)                          \
          bf[n][kh] = *(const short8*)&Bs[BUF][rb][((kh * 4 + quad) ^ (rb & 7)) * 8];\
      }                                                                           \
    }                                                                             \
    STAGE;                                                                        \
    __builtin_amdgcn_s_barrier();                                                 \
    asm volatile("s_waitcnt lgkmcnt(0)" ::: "memory");                            \
    __builtin_amdgcn_sched_barrier(0);                                            \
    __builtin_amdgcn_s_setprio(1);                                                \
    _Pragma("unroll") for (int kh = 0; kh < 2; ++kh)                              \
      _Pragma("unroll") for (int m2 = 0; m2 < 2; ++m2)                            \
        _Pragma("unroll") for (int n = 0; n < 4; ++n)                             \
          acc[2 * (Q) + m2][n] = __builtin_amdgcn_mfma_f32_16x16x32_bf16(         \
              af[m2][kh], bf[n][kh], acc[2 * (Q) + m2][n], 0, 0, 0);              \
    __builtin_amdgcn_s_setprio(0);                                                \
    __builtin_amdgcn_sched_barrier(0);                                            \
    VMW;                                                                          \
    __builtin_amdgcn_s_barrier();                                                 \
    __builtin_amdgcn_sched_barrier(0);                                            \
  } while (0)

  // ---- prologue: tile0 complete + tile1 {B0,B1,A1}; 3 stages left in flight
  stageB(0, 0, 0); stageB(0, 1, 0); stageA(0, 0, 0); stageA(0, 1, 0);
  stageB(1, 0, 1); stageB(1, 1, 1); stageA(1, 0, 1);
  asm volatile("s_waitcnt vmcnt(6)" ::: "memory");
  __builtin_amdgcn_s_barrier();
  __builtin_amdgcn_sched_barrier(0);

  constexpr int NIT = K / 128;   // 2 K-tiles per iteration
#pragma unroll 1
  for (int i = 0; i < NIT - 1; ++i) {
    const int t1 = 2 * i + 1, t2 = 2 * i + 2, t3 = 2 * i + 3;
    PH(0, 0, stageA(t1, 1, 1), );
    PH(0, 1, stageB(t2, 0, 0), );
    PH(0, 2, stageB(t2, 1, 0), );
    PH(0, 3, stageA(t2, 0, 0), asm volatile("s_waitcnt vmcnt(6)" ::: "memory"));
    PH(1, 0, stageA(t2, 1, 0), );
    PH(1, 1, stageB(t3, 0, 1), );
    PH(1, 2, stageB(t3, 1, 1), );
    PH(1, 3, stageA(t3, 0, 1), asm volatile("s_waitcnt vmcnt(6)" ::: "memory"));
  }
  // ---- last iteration: only A2 of the final (odd) tile remains to stage
  PH(0, 0, stageA(2 * NIT - 1, 1, 1), );
  PH(0, 1, , );
  PH(0, 2, , );
  PH(0, 3, , asm volatile("s_waitcnt vmcnt(0)" ::: "memory"));
  PH(1, 0, , );
  PH(1, 1, , );
  PH(1, 2, , );
  PH(1, 3, , );
#undef PH
}

// ---- GEMM1: tokens [M,1024] x wqT^T -> qkv bf16 [M,1536] ----
__global__ __launch_bounds__(512) void k_gemm_qkv(const __hip_bfloat16* __restrict__ A,
                                                  const __hip_bfloat16* __restrict__ Bt,
                                                  __hip_bfloat16* __restrict__ Cmat) {
  __shared__ __hip_bfloat16 As[2][256][64];
  __shared__ __hip_bfloat16 Bs[2][256][64];
  const int tid = threadIdx.x;
  const int bid = blockIdx.x;
  const int swz = (bid & 7) * 96 + (bid >> 3);   // 768 blocks, bijective XCD swizzle
  const int n0 = (swz % 6) * 256, m0 = (swz / 6) * 256;  // n-major: A-tile L2 reuse
  floatx4 acc[8][4] = {};
  gemm256_acc<1024>(A, Bt, m0, n0, tid, As, Bs, acc);
  const int lane = tid & 63, wid = tid >> 6;
  const int wm = wid >> 2, wn = wid & 3;
  const int l15 = lane & 15, quad = lane >> 4;
#pragma unroll
  for (int mt = 0; mt < 8; ++mt)
#pragma unroll
    for (int nt = 0; nt < 4; ++nt) {
      const int col = n0 + wn * 64 + nt * 16 + l15;
#pragma unroll
      for (int r = 0; r < 4; ++r) {
        const int row = m0 + wm * 128 + mt * 16 + quad * 4 + r;
        Cmat[(size_t)row * 1536 + col] = __float2bfloat16(acc[mt][nt][r]);
      }
    }
}

// ---- attention: one block per (window, head); swizzled Q/K, bank-clean V transpose ----
__global__ __launch_bounds__(256) void k_attn(const __hip_bfloat16* __restrict__ qkv,
                                              __hip_bfloat16* __restrict__ oattn) {
  __shared__ __hip_bfloat16 Qs[64 * 64];   // [t][dh] swizzled chunks
  __shared__ __hip_bfloat16 Ks[64 * 64];   // [t][dh] swizzled chunks
  __shared__ __hip_bfloat16 Vt[64 * 72];   // [dh][t] padded
  __shared__ __hip_bfloat16 Ps[64 * 72];   // [t][t'] padded; first reused as swizzled Vs[64*64]
  const int win = blockIdx.x, head = blockIdx.y;
  const int tid = threadIdx.x, lane = tid & 63, wid = tid >> 6;
  const int l15 = lane & 15, quad = lane >> 4;
  const int sx = l15 & 7;
  const size_t base = (size_t)win * 64 * 1536 + head * 64;
  for (int l = 0; l < 2; ++l) {
    int idx = l * 256 + tid;
    int t = idx >> 3, ch = idx & 7;
    const size_t rowb = base + (size_t)t * 1536 + ch * 8;
    uint4 q = *(const uint4*)&qkv[rowb];
    uint4 k = *(const uint4*)&qkv[rowb + 512];
    uint4 v = *(const uint4*)&qkv[rowb + 1024];
    const int pos = (ch ^ (t & 7)) * 8;
    *(uint4*)&Qs[t * 64 + pos] = q;
    *(uint4*)&Ks[t * 64 + pos] = k;
    *(uint4*)&Ps[t * 64 + pos] = v;       // Vs staging (swizzled), Ps not yet live
  }
  __syncthreads();
  // transpose V: Vs (swizzled [t][dh]) -> Vt [dh][t]
  {
    const int t = tid & 63, w = tid >> 6;
#pragma unroll
    for (int jn = 0; jn < 2; ++jn) {
      int j = w * 2 + jn;                                  // dh chunk
      short8 v = *(const short8*)&Ps[t * 64 + ((j ^ (t & 7)) * 8)];
#pragma unroll
      for (int jj = 0; jj < 8; ++jj) Vt[(j * 8 + jj) * 72 + t] = ((__hip_bfloat16*)&v)[jj];
    }
  }
  __syncthreads();   // Vs reads done; Ps may now be overwritten by softmax
  // S = Q K^T * scale
  floatx4 sacc[4] = {};
#pragma unroll
  for (int kk = 0; kk < 64; kk += 32) {
    const int pos = (((kk >> 3) + quad) ^ sx) * 8;
    short8 aq = *(const short8*)&Qs[(wid * 16 + l15) * 64 + pos];
#pragma unroll
    for (int ct = 0; ct < 4; ++ct) {
      short8 bk = *(const short8*)&Ks[(ct * 16 + l15) * 64 + pos];
      sacc[ct] = __builtin_amdgcn_mfma_f32_16x16x32_bf16(aq, bk, sacc[ct], 0, 0, 0);
    }
  }
#pragma unroll
  for (int ct = 0; ct < 4; ++ct)
#pragma unroll
    for (int r = 0; r < 4; ++r) sacc[ct][r] = sacc[ct][r] * 0.125f;
  // softmax per row
#pragma unroll
  for (int r = 0; r < 4; ++r) {
    float m = fmaxf(fmaxf(sacc[0][r], sacc[1][r]), fmaxf(sacc[2][r], sacc[3][r]));
    m = fmaxf(m, __shfl_xor(m, 1));
    m = fmaxf(m, __shfl_xor(m, 2));
    m = fmaxf(m, __shfl_xor(m, 4));
    m = fmaxf(m, __shfl_xor(m, 8));
    float ev[4]; float s0 = 0.f;
#pragma unroll
    for (int ct = 0; ct < 4; ++ct) { ev[ct] = __expf(sacc[ct][r] - m); s0 += ev[ct]; }
    s0 += __shfl_xor(s0, 1);
    s0 += __shfl_xor(s0, 2);
    s0 += __shfl_xor(s0, 4);
    s0 += __shfl_xor(s0, 8);
    float inv = 1.0f / s0;
    int row = wid * 16 + quad * 4 + r;
#pragma unroll
    for (int ct = 0; ct < 4; ++ct)
      Ps[row * 72 + ct * 16 + l15] = __float2bfloat16(ev[ct] * inv);
  }
  __syncthreads();
  // O = P V
  floatx4 oacc[4] = {};
#pragma unroll
  for (int kk = 0; kk < 64; kk += 32) {
    const int q8 = quad * 8;
    short8 ap = *(const short8*)&Ps[(wid * 16 + l15) * 72 + kk + q8];
#pragma unroll
    for (int nt = 0; nt < 4; ++nt) {
      short8 bv = *(const short8*)&Vt[(nt * 16 + l15) * 72 + kk + q8];
      oacc[nt] = __builtin_amdgcn_mfma_f32_16x16x32_bf16(ap, bv, oacc[nt], 0, 0, 0);
    }
  }
#pragma unroll
  for (int nt = 0; nt < 4; ++nt) {
    int dh = nt * 16 + l15;
#pragma unroll
    for (int r = 0; r < 4; ++r) {
      int t = wid * 16 + quad * 4 + r;
      oattn[((size_t)win * 64 + t) * 512 + head * 64 + dh] = __float2bfloat16(oacc[nt][r]);
    }
  }
}

// ---- GEMM2 + bias + un-patchify scatter ----
__global__ __launch_bounds__(512) void k_gemm_out(const __hip_bfloat16* __restrict__ A,
                                                  const __hip_bfloat16* __restrict__ Bt,
                                                  const float* __restrict__ bias,
                                                  float* __restrict__ out) {
  __shared__ __hip_bfloat16 As[2][256][64];
  __shared__ __hip_bfloat16 Bs[2][256][64];
  const int tid = threadIdx.x;
  const int bid = blockIdx.x;
  const int swz = (bid & 7) * 64 + (bid >> 3);   // 512 blocks
  const int n0 = (swz & 3) * 256, m0 = (swz >> 2) * 256;
  floatx4 acc[8][4] = {};
  gemm256_acc<512>(A, Bt, m0, n0, tid, As, Bs, acc);
  const int lane = tid & 63, wid = tid >> 6;
  const int wm = wid >> 2, wn = wid & 3;
  const int l15 = lane & 15, quad = lane >> 4;
#pragma unroll
  for (int nt = 0; nt < 4; ++nt) {
    const int dp = n0 + wn * 64 + nt * 16 + l15;
    const float bv = bias[dp];
    const int c = dp >> 4, p1 = (dp >> 2) & 3, p2 = dp & 3;
#pragma unroll
    for (int mt = 0; mt < 8; ++mt)
#pragma unroll
      for (int r = 0; r < 4; ++r) {
        const int m = m0 + wm * 128 + mt * 16 + quad * 4 + r;
        const int win = m >> 6, t = m & 63;
        const int i = t >> 3, j = t & 7;
        const int b = win >> 6, h1 = (win >> 3) & 7, w1 = win & 7;
        const int h = h1 * 32 + i * 4 + p1, w = w1 * 32 + j * 4 + p2;
        out[((b * 64 + c) * 256 + h) * 256 + w] = acc[mt][nt][r] + bv;
      }
  }
}

extern "C" void kernel_launch(void* const* d_in, const int* in_sizes, int n_in,
                              void* d_out, int out_size, void* d_ws, size_t ws_size,
                              hipStream_t stream) {
  const float* x    = (const float*)d_in[0];
  const float* wqkv = (const float*)d_in[1];
  const float* wout = (const float*)d_in[2];
  const float* bout = (const float*)d_in[3];
  float* out = (float*)d_out;
  char* ws = (char*)d_ws;
  if (ws_size < WS_NEED) return;

  __hip_bfloat16* tokA  = (__hip_bfloat16*)(ws + OFF_TOKA);
  __hip_bfloat16* oattn = (__hip_bfloat16*)(ws + OFF_TOKA);  // aliases tokA (dead after GEMM1)
  __hip_bfloat16* qkv   = (__hip_bfloat16*)(ws + OFF_QKV);
  __hip_bfloat16* wqT   = (__hip_bfloat16*)(ws + OFF_WQT);
  __hip_bfloat16* woT   = (__hip_bfloat16*)(ws + OFF_WOT);
  float* boP = (float*)(ws + OFF_BO);

  k_perm_wqkv<<<96, 256, 0, stream>>>(wqkv, wqT);
  k_perm_wout<<<32, 256, 0, stream>>>(wout, woT);
  k_perm_bias<<<4, 256, 0, stream>>>(bout, boP);
  k_patchify<<<4096, 256, 0, stream>>>(x, tokA);
  k_gemm_qkv<<<768, 512, 0, stream>>>(tokA, wqT, qkv);
  k_attn<<<dim3(512, 8), 256, 0, stream>>>(qkv, oattn);
  k_gemm_out<<<512, 512, 0, stream>>>(oattn, woT, boP, out);
}